// Round 11
// baseline (685.815 us; speedup 1.0000x reference)
//
#include <hip/hip_runtime.h>
#include <float.h>

// Sparsemax attention v5: streaming rematerialization.
// B=2,H=16,S=2048,D=64 fp32, temperature 8.
//
// Round-10 machinery (swapped QK^T, deterministic candidate collect, in-wave
// list Michelot + full-scan fallback, PV shuffle-transpose, split-K reduce)
// but NO persistent score registers: three streaming passes over the same
// MFMAs (rowmax -> collect -> PV), rematerializing the 4-reg score tile per
// 16-col step. Breaks the 124-reg/4-waves-per-SIMD wall; LDS unioned to
// 33.3 KB -> 3-4 blocks/CU.

#define S_LEN 2048
#define DHEAD 64
#define BROWS 16
#define NWAVES 8
#define FB_ITERS 12
#define LCAP 8

typedef _Float16 f16x8 __attribute__((ext_vector_type(8)));
typedef __attribute__((ext_vector_type(4))) float f32x4;
typedef __attribute__((ext_vector_type(8))) unsigned short u16x8;

__device__ __forceinline__ unsigned short f2h(float x) {
    return __builtin_bit_cast(unsigned short, (_Float16)x);
}
__device__ __forceinline__ unsigned int pk2h(float lo, float hi) {
    return (unsigned int)f2h(lo) | ((unsigned int)f2h(hi) << 16);
}
__device__ __forceinline__ f16x8 cvt8h(float4 a, float4 b) {
    union { unsigned int u[4]; f16x8 v; } r;
    r.u[0] = pk2h(a.x, a.y); r.u[1] = pk2h(a.z, a.w);
    r.u[2] = pk2h(b.x, b.y); r.u[3] = pk2h(b.z, b.w);
    return r.v;
}

__global__ __launch_bounds__(256)
void cvt_f16_kernel(const float* __restrict__ src, uint4* __restrict__ dst, int n8) {
    int i = blockIdx.x * 256 + threadIdx.x;
    if (i >= n8) return;
    const float4* s4 = reinterpret_cast<const float4*>(src);
    float4 a = s4[2 * i], b = s4[2 * i + 1];
    uint4 o;
    o.x = pk2h(a.x, a.y); o.y = pk2h(a.z, a.w);
    o.z = pk2h(b.x, b.y); o.w = pk2h(b.z, b.w);
    dst[i] = o;
}

// V[bh][2048][64] fp32 -> VT[bh][64][2048] fp16, 64x64 tiles via LDS
__global__ __launch_bounds__(256)
void vt_kernel(const float* __restrict__ V, unsigned short* __restrict__ VT) {
    __shared__ unsigned short tile[64][72];   // +8 pad
    const int t  = threadIdx.x;
    const int bh = blockIdx.x >> 5;           // 32 s-tiles per bh
    const int s0 = (blockIdx.x & 31) * 64;
    const float* Vb = V + ((size_t)bh * S_LEN + s0) * DHEAD;
    const int r = t >> 2, q = t & 3;
    #pragma unroll
    for (int j = 0; j < 4; ++j) {
        float4 v4 = *reinterpret_cast<const float4*>(Vb + (size_t)r * DHEAD + q * 16 + j * 4);
        tile[r][q * 16 + j * 4 + 0] = f2h(v4.x);
        tile[r][q * 16 + j * 4 + 1] = f2h(v4.y);
        tile[r][q * 16 + j * 4 + 2] = f2h(v4.z);
        tile[r][q * 16 + j * 4 + 3] = f2h(v4.w);
    }
    __syncthreads();
    const int d = t >> 2;
    union { unsigned short s[16]; u16x8 v[2]; } o;
    #pragma unroll
    for (int i = 0; i < 16; ++i) o.s[i] = tile[q * 16 + i][d];
    u16x8* dst = reinterpret_cast<u16x8*>(VT + ((size_t)bh * DHEAD + d) * S_LEN + s0 + q * 16);
    dst[0] = o.v[0];
    dst[1] = o.v[1];
}

__global__ __launch_bounds__(512, 6)
void spx_main(const float* __restrict__ Q,
              const unsigned short* __restrict__ Kh,
              const unsigned short* __restrict__ VT,
              float* __restrict__ O)
{
    // LDS union: region A (collect/Michelot, 21.2 KB) aliased by s_red (33.3 KB)
    __shared__ __align__(16) char smem[33280];
    float (*s_lv)[256]     = reinterpret_cast<float(*)[256]>(smem);            // 16 KB
    int   (*s_lc)[NWAVES][4] = reinterpret_cast<int(*)[NWAVES][4]>(smem + 16384); // 2 KB
    float (*s_pm)[BROWS]   = reinterpret_cast<float(*)[BROWS]>(smem + 18432); // 512 B
    float (*s_ps)[NWAVES][BROWS] = reinterpret_cast<float(*)[NWAVES][BROWS]>(smem + 18944); // 1 KB
    float (*s_pc)[NWAVES][BROWS] = reinterpret_cast<float(*)[NWAVES][BROWS]>(smem + 19968); // 1 KB
    float *s_rm            = reinterpret_cast<float*>(smem + 20992);
    float *s_tau           = reinterpret_cast<float*>(smem + 21056);
    int   *s_ovf           = reinterpret_cast<int*>(smem + 21120);
    float (*s_red)[BROWS][65] = reinterpret_cast<float(*)[BROWS][65]>(smem);  // 33.28 KB

    const int t  = threadIdx.x;
    const int w  = t >> 6;
    const int l  = t & 63;
    const int lm = l & 15;
    const int lk = l >> 4;

    int bid = blockIdx.x;
    if (((int)gridDim.x & 7) == 0)
        bid = (bid & 7) * ((int)gridDim.x >> 3) + (bid >> 3);   // XCD swizzle
    const int nrb  = S_LEN / BROWS;                  // 128
    const int bh   = bid / nrb;
    const int row0 = (bid % nrb) * BROWS;

    const size_t bhoff = (size_t)bh * S_LEN * DHEAD;
    const float* Qf = Q + bhoff;
    const unsigned short* KhB = Kh + bhoff;
    const unsigned short* VTb = VT + bhoff;
    float* Of = O + bhoff;

    if (t == 0) *s_ovf = 0;

    // ---- Q^T B-fragments: lane (lm,lk) = Q[row0+lm][kp*32 + lk*8 + j] ----
    f16x8 qfrag[2];
    #pragma unroll
    for (int kp = 0; kp < 2; ++kp) {
        const float* qp = Qf + (size_t)(row0 + lm) * DHEAD + kp * 32 + lk * 8;
        qfrag[kp] = cvt8h(*reinterpret_cast<const float4*>(qp),
                          *reinterpret_cast<const float4*>(qp + 4));
    }

    const int col0 = w * (S_LEN / NWAVES);           // 256-wide slab

    // score tile rematerializer: S[qrow=lm][col0 + ct*16 + lk*4 + e]
    #define SCORE_TILE(a_, ct_)                                                  \
        {                                                                        \
            const unsigned short* kp8_ = KhB + (size_t)(col0 + (ct_) * 16 + lm) * DHEAD; \
            f16x8 k0_ = *reinterpret_cast<const f16x8*>(kp8_ + lk * 8);          \
            f16x8 k1_ = *reinterpret_cast<const f16x8*>(kp8_ + 32 + lk * 8);     \
            a_ = (f32x4){0.f, 0.f, 0.f, 0.f};                                    \
            a_ = __builtin_amdgcn_mfma_f32_16x16x32_f16(k0_, qfrag[0], a_, 0, 0, 0); \
            a_ = __builtin_amdgcn_mfma_f32_16x16x32_f16(k1_, qfrag[1], a_, 0, 0, 0); \
        }

    // ---- pass 1: row max (row = lm) ----
    float mx;
    {
        float m = -FLT_MAX;
        #pragma unroll
        for (int ct = 0; ct < 16; ++ct) {
            f32x4 a;
            SCORE_TILE(a, ct);
            #pragma unroll
            for (int e = 0; e < 4; ++e) m = fmaxf(m, a[e]);
        }
        m = fmaxf(m, __shfl_xor(m, 16));
        m = fmaxf(m, __shfl_xor(m, 32));
        if (lk == 0) s_pm[w][lm] = m;
    }
    __syncthreads();
    {
        float m = s_pm[0][lm];
        #pragma unroll
        for (int ww = 1; ww < NWAVES; ++ww) m = fmaxf(m, s_pm[ww][lm]);
        mx = m;
    }
    if (w == 0 && lk == 0) s_rm[lm] = mx;

    // ---- pass 2: candidate collect {s > mx-8} -> deterministic LDS slots ----
    {
        const float thr0 = mx - 8.f;
        const int base = w * 32 + lk * 8;
        int own = 0;
        bool of = false;
        #pragma unroll
        for (int ct = 0; ct < 16; ++ct) {
            f32x4 a;
            SCORE_TILE(a, ct);
            #pragma unroll
            for (int e = 0; e < 4; ++e) {
                const float v = a[e];
                if (v > thr0) {
                    if (own < LCAP) { s_lv[lm][base + own] = v; ++own; }
                    else of = true;
                }
            }
        }
        s_lc[lm][w][lk] = own;
        if (of) atomicOr(s_ovf, 1);
    }
    __syncthreads();

    float tauF;
    if (*s_ovf == 0) {
        // ---- in-wave list Michelot: wave w owns rows {2w, 2w+1} ----
        const int r0 = w * 2;
        float cv[8];
        #pragma unroll
        for (int q = 0; q < 8; ++q) {
            const int row  = r0 + (q >> 2);
            const int slot = (q & 3) * 64 + l;
            const int cnt  = s_lc[row][slot >> 5][(slot >> 3) & 3];
            const float v  = s_lv[row][slot];
            cv[q] = ((slot & 7) < cnt) ? v : -FLT_MAX;
        }
        float tv0 = s_rm[r0] - 8.f;
        float tv1 = s_rm[r0 + 1] - 8.f;
        int c0p = -1, c1p = -1;
        for (int it = 0; it < 16; ++it) {
            float s0 = 0.f, c0 = 0.f, s1 = 0.f, c1 = 0.f;
            #pragma unroll
            for (int q = 0; q < 4; ++q) {
                const float v = cv[q]; const bool in = v > tv0;
                s0 += in ? v : 0.f;  c0 += in ? 1.f : 0.f;
            }
            #pragma unroll
            for (int q = 4; q < 8; ++q) {
                const float v = cv[q]; const bool in = v > tv1;
                s1 += in ? v : 0.f;  c1 += in ? 1.f : 0.f;
            }
            #pragma unroll
            for (int o = 1; o < 64; o <<= 1) {
                s0 += __shfl_xor(s0, o); c0 += __shfl_xor(c0, o);
                s1 += __shfl_xor(s1, o); c1 += __shfl_xor(c1, o);
            }
            tv0 = (s0 - 8.f) / c0;
            tv1 = (s1 - 8.f) / c1;
            const int C0 = (int)c0, C1 = (int)c1;
            if (C0 == c0p && C1 == c1p) break;   // fixpoint: exact tau
            c0p = C0; c1p = C1;
        }
        if (l == 0) { s_tau[r0] = tv0; s_tau[r0 + 1] = tv1; }
        __syncthreads();
        tauF = s_tau[lm];
    } else {
        // ---- fallback: full-scan Michelot with rematerialized scores ----
        float tv = mx - 8.f;
        for (int it = 0; it < FB_ITERS; ++it) {
            float s = 0.f, c = 0.f;
            #pragma unroll
            for (int ct = 0; ct < 16; ++ct) {
                f32x4 a;
                SCORE_TILE(a, ct);
                #pragma unroll
                for (int e = 0; e < 4; ++e) {
                    const float v = a[e];
                    const bool in = v > tv;
                    s += in ? v : 0.f;
                    c += in ? 1.f : 0.f;
                }
            }
            s += __shfl_xor(s, 16); s += __shfl_xor(s, 32);
            c += __shfl_xor(c, 16); c += __shfl_xor(c, 32);
            const int slot = it & 1;
            if (lk == 0) { s_ps[slot][w][lm] = s; s_pc[slot][w][lm] = c; }
            __syncthreads();
            float S = 0.f, C = 0.f;
            #pragma unroll
            for (int ww = 0; ww < NWAVES; ++ww) {
                S += s_ps[slot][ww][lm];
                C += s_pc[slot][ww][lm];
            }
            tv = (S - 8.f) / C;
        }
        tauF = tv;
    }

    // ---- pass 3: PV with rematerialized p; pack/shuffle -> B-frag -> MFMA ----
    f32x4 pv[4];
    #pragma unroll
    for (int d0 = 0; d0 < 4; ++d0) pv[d0] = (f32x4){0.f, 0.f, 0.f, 0.f};

    const int srcA = lm + 32 * (lk & 1);     // lane holding kcols (lk&1)*8+0..3
    const int srcB = srcA + 16;              // +4..7
    const bool hiCt = (lk >> 1) != 0;        // this lane's chunk-half: ct=2ch+1?

    #pragma unroll
    for (int ch = 0; ch < 8; ++ch) {
        f32x4 aA, aB;
        SCORE_TILE(aA, 2 * ch);
        SCORE_TILE(aB, 2 * ch + 1);
        const unsigned int pA0 = pk2h(fmaxf(aA[0] - tauF, 0.f), fmaxf(aA[1] - tauF, 0.f));
        const unsigned int pA1 = pk2h(fmaxf(aA[2] - tauF, 0.f), fmaxf(aA[3] - tauF, 0.f));
        const unsigned int pB0 = pk2h(fmaxf(aB[0] - tauF, 0.f), fmaxf(aB[1] - tauF, 0.f));
        const unsigned int pB1 = pk2h(fmaxf(aB[2] - tauF, 0.f), fmaxf(aB[3] - tauF, 0.f));
        const unsigned int xA0 = (unsigned int)__shfl((int)pA0, srcA);
        const unsigned int xB0 = (unsigned int)__shfl((int)pB0, srcA);
        const unsigned int xA1 = (unsigned int)__shfl((int)pA1, srcA);
        const unsigned int xB1 = (unsigned int)__shfl((int)pB1, srcA);
        const unsigned int yA0 = (unsigned int)__shfl((int)pA0, srcB);
        const unsigned int yB0 = (unsigned int)__shfl((int)pB0, srcB);
        const unsigned int yA1 = (unsigned int)__shfl((int)pA1, srcB);
        const unsigned int yB1 = (unsigned int)__shfl((int)pB1, srcB);
        union { unsigned int u[4]; f16x8 v; } pf;
        pf.u[0] = hiCt ? xB0 : xA0;
        pf.u[1] = hiCt ? xB1 : xA1;
        pf.u[2] = hiCt ? yB0 : yA0;
        pf.u[3] = hiCt ? yB1 : yA1;
        #pragma unroll
        for (int d0 = 0; d0 < 4; ++d0) {
            const unsigned short* vp = VTb + (size_t)(d0 * 16 + lm) * S_LEN
                                           + col0 + ch * 32 + lk * 8;
            f16x8 vfrag = *reinterpret_cast<const f16x8*>(vp);
            pv[d0] = __builtin_amdgcn_mfma_f32_16x16x32_f16(vfrag, pf.v, pv[d0], 0, 0, 0);
        }
    }

    // region A fully read; hand LDS to s_red
    __syncthreads();

    // ---- split-K reduce: pv[d0][e] = O^T[dim=d0*16+lk*4+e][qrow=lm] ----
    #pragma unroll
    for (int d0 = 0; d0 < 4; ++d0)
        #pragma unroll
        for (int e = 0; e < 4; ++e)
            s_red[w][lm][d0 * 16 + lk * 4 + e] = pv[d0][e];
    __syncthreads();

    #pragma unroll
    for (int rep = 0; rep < 2; ++rep) {
        const int idx = t + rep * 512;
        const int qr  = idx >> 6;
        const int d   = idx & 63;
        float o = 0.f;
        #pragma unroll
        for (int ww = 0; ww < NWAVES; ++ww) o += s_red[ww][qr][d];
        Of[(size_t)(row0 + qr) * DHEAD + d] = o * 0.125f;
    }
    #undef SCORE_TILE
}

extern "C" void kernel_launch(void* const* d_in, const int* in_sizes, int n_in,
                              void* d_out, int out_size, void* d_ws, size_t ws_size,
                              hipStream_t stream) {
    const float* q = (const float*)d_in[0];
    const float* k = (const float*)d_in[1];
    const float* v = (const float*)d_in[2];
    float* out = (float*)d_out;

    const int nElem = in_sizes[0];                    // B*H*S*D
    const int BH    = nElem / (S_LEN * DHEAD);

    unsigned short* kh = (unsigned short*)d_ws;
    unsigned short* vt = kh + nElem;

    const int n8 = nElem / 8;
    cvt_f16_kernel<<<(n8 + 255) / 256, 256, 0, stream>>>(k, (uint4*)kh, n8);
    vt_kernel<<<BH * (S_LEN / 64), 256, 0, stream>>>(v, vt);
    spx_main<<<BH * (S_LEN / BROWS), 512, 0, stream>>>(q, kh, vt, out);
}